// Round 20
// baseline (127.817 us; speedup 1.0000x reference)
//
#include <hip/hip_runtime.h>
#include <cstdint>
#include <cstddef>

#define NB 2048
#define NT 512
#define ND 64
#define NR 50
#define NE 4             // batch elements per block
#define REVP 68          // review row stride (floats)
#define BFULL 65536      // full B LDS bytes (16 ksteps x 4 n x 64 lanes x 16B)

typedef __attribute__((ext_vector_type(8))) short bf16x8;
typedef __attribute__((ext_vector_type(4))) float f32x4;

__device__ inline unsigned short f2bf_rne(float x) {
    unsigned int u = __float_as_uint(x);
    u += 0x7fffu + ((u >> 16) & 1u);
    return (unsigned short)(u >> 16);
}

__device__ inline bf16x8 cvt8_rne(float4 v0, float4 v1) {
    union { unsigned int u[4]; bf16x8 v; } P;
    asm("v_cvt_pk_bf16_f32 %0, %1, %2" : "=v"(P.u[0]) : "v"(v0.x), "v"(v0.y));
    asm("v_cvt_pk_bf16_f32 %0, %1, %2" : "=v"(P.u[1]) : "v"(v0.z), "v"(v0.w));
    asm("v_cvt_pk_bf16_f32 %0, %1, %2" : "=v"(P.u[2]) : "v"(v1.x), "v"(v1.y));
    asm("v_cvt_pk_bf16_f32 %0, %1, %2" : "=v"(P.u[3]) : "v"(v1.z), "v"(v1.w));
    return P.v;
}

__device__ inline void gload16(const void* gsrc, void* ldst) {
    __builtin_amdgcn_global_load_lds(
        (const __attribute__((address_space(1))) unsigned int*)gsrc,
        (__attribute__((address_space(3))) unsigned int*)ldst, 16, 0, 0);
}

// ---------------------------------------------------------------------------
__global__ __launch_bounds__(256) void prep_kernel(
    const float* __restrict__ tw,
    const float* __restrict__ fc_u_w, const float* __restrict__ fc_ru_w,
    const float* __restrict__ fc_i_w, const float* __restrict__ fc_ri_w,
    unsigned short* __restrict__ bhi,
    unsigned short* __restrict__ fuhi, unsigned short* __restrict__ fihi)
{
    int i = blockIdx.x * 256 + threadIdx.x;          // 192*256 = 49152
    if (i < 32768) {
        int j  = i & 7;
        int l  = (i >> 3) & 63;
        int n  = (i >> 9) & 3;
        int kk = i >> 11;                            // 0..15
        int t = kk * 32 + ((l >> 4) << 3) + j;
        int d = n * 16 + (l & 15);
        bhi[i] = f2bf_rne(tw[t * ND + d]);
    } else {
        int q = i - 32768;                           // 0..16383
        int br = q >> 13;                            // 0 user, 1 item
        int e = q & 8191;
        int j  = e & 7;
        int l  = (e >> 3) & 63;
        int n  = (e >> 9) & 3;
        int kk = e >> 11;                            // 0..3
        int k = kk * 32 + ((l >> 4) << 3) + j;       // 0..127
        int col = n * 16 + (l & 15);
        const float* W = (k < 64) ? (br ? fc_ri_w : fc_ru_w)
                                  : (br ? fc_i_w  : fc_u_w);
        unsigned short hi = f2bf_rne(W[(k & 63) * ND + col]);
        if (br) fihi[e] = hi; else fuhi[e] = hi;
    }
}

// ---------------------------------------------------------------------------
__global__ __launch_bounds__(256) void colsum_kernel(const float* __restrict__ tw,
                                                     float* __restrict__ colsum) {
    __shared__ float part[4][ND];
    int d = threadIdx.x & 63, p = threadIdx.x >> 6;
    float s = 0.f;
    for (int t = p; t < NT; t += 4) s += tw[t * ND + d];
    part[p][d] = s;
    __syncthreads();
    if (threadIdx.x < ND)
        colsum[d] = part[0][d] + part[1][d] + part[2][d] + part[3][d];
}

// pinned issue of ONE kstep's A fragment (8 floats of this lane's own row)
#define AISS2(T, e, COL)                                                       \
    float4 aA_##T##_0, aA_##T##_1;                                             \
    {                                                                          \
        const float* _p = arowp[e] + (size_t)rowc * NT + (COL);                \
        asm volatile("global_load_dwordx4 %0, %1, off"                         \
                     : "=v"(aA_##T##_0) : "v"(_p) : "memory");                 \
        asm volatile("global_load_dwordx4 %0, %1, off"                         \
                     : "=v"(aA_##T##_1) : "v"(_p + 4) : "memory");             \
    }
// 16 loads = one elem's K-half (8 ksteps)
#define AISS16(T, e, h)                                                        \
    AISS2(T##_0, e, (h) * 256 + 0 * 32 + g * 8)                                \
    AISS2(T##_1, e, (h) * 256 + 1 * 32 + g * 8)                                \
    AISS2(T##_2, e, (h) * 256 + 2 * 32 + g * 8)                                \
    AISS2(T##_3, e, (h) * 256 + 3 * 32 + g * 8)                                \
    AISS2(T##_4, e, (h) * 256 + 4 * 32 + g * 8)                                \
    AISS2(T##_5, e, (h) * 256 + 5 * 32 + g * 8)                                \
    AISS2(T##_6, e, (h) * 256 + 6 * 32 + g * 8)                                \
    AISS2(T##_7, e, (h) * 256 + 7 * 32 + g * 8)

// interlocked retire+convert -> bf16x8 fragment fr_<T>.v
#define FRAG(T, N)                                                             \
    union { unsigned int u[4]; bf16x8 v; } fr_##T;                             \
    asm volatile("s_waitcnt vmcnt(" #N ")\n\t"                                 \
                 "v_cvt_pk_bf16_f32 %0, %4, %5\n\t"                            \
                 "v_cvt_pk_bf16_f32 %1, %6, %7\n\t"                            \
                 "v_cvt_pk_bf16_f32 %2, %8, %9\n\t"                            \
                 "v_cvt_pk_bf16_f32 %3, %10, %11"                              \
                 : "=&v"(fr_##T.u[0]), "=&v"(fr_##T.u[1]),                     \
                   "=&v"(fr_##T.u[2]), "=&v"(fr_##T.u[3])                      \
                 : "v"(aA_##T##_0.x), "v"(aA_##T##_0.y),                       \
                   "v"(aA_##T##_0.z), "v"(aA_##T##_0.w),                       \
                   "v"(aA_##T##_1.x), "v"(aA_##T##_1.y),                       \
                   "v"(aA_##T##_1.z), "v"(aA_##T##_1.w)                        \
                 : "memory");
// retire a 16-load half with 16 more loads behind it: ladder 30..16
#define ARETH(T)                                                               \
    FRAG(T##_0, 30) FRAG(T##_1, 28) FRAG(T##_2, 26) FRAG(T##_3, 24)            \
    FRAG(T##_4, 22) FRAG(T##_5, 20) FRAG(T##_6, 18) FRAG(T##_7, 16)
// retire the LAST 16-load half (nothing behind): ladder 14..0
#define ARETL(T)                                                               \
    FRAG(T##_0, 14) FRAG(T##_1, 12) FRAG(T##_2, 10) FRAG(T##_3, 8)             \
    FRAG(T##_4, 6)  FRAG(T##_5, 4)  FRAG(T##_6, 2)  FRAG(T##_7, 0)
// compute one elem's half (8 ksteps)
#define QCOMP8(T, e, h)                                                        \
    kstep((h) * 8 + 0, fr_##T##_0.v, e); kstep((h) * 8 + 1, fr_##T##_1.v, e);  \
    kstep((h) * 8 + 2, fr_##T##_2.v, e); kstep((h) * 8 + 3, fr_##T##_3.v, e);  \
    kstep((h) * 8 + 4, fr_##T##_4.v, e); kstep((h) * 8 + 5, fr_##T##_5.v, e);  \
    kstep((h) * 8 + 6, fr_##T##_6.v, e); kstep((h) * 8 + 7, fr_##T##_7.v, e);

// ---------------------------------------------------------------------------
// Block = 4 waves x 4 batch elements (grid 1024), 2 blocks/CU, 256-VGPR cap.
// FULL B in LDS (64KB), staged ONCE -- zero barriers in the K-loop.
// A: rolling 32-deep pinned pipeline (16KB/wave constantly in flight):
// retire half X (fused vmcnt ladder) || issue half X+1 || compute X.
// B/fc global traffic amortized x4 (65+17 MB vs r19's 131+34).
__global__ __launch_bounds__(256, 2) void branch_kernel(
    const int* __restrict__ user, const int* __restrict__ item,
    const float* __restrict__ user_r_topic, const float* __restrict__ item_r_topic,
    const float* __restrict__ user_embed_w, const float* __restrict__ item_embed_w,
    const float* __restrict__ user_att_w, const float* __restrict__ item_att_w,
    const unsigned short* __restrict__ bhi,
    const unsigned short* __restrict__ fuhi, const unsigned short* __restrict__ fihi,
    const float* __restrict__ fc_u_b, const float* __restrict__ fc_ru_b,
    const float* __restrict__ fc_i_b, const float* __restrict__ fc_ri_b,
    const float* __restrict__ h_u_w, const float* __restrict__ h_u_b,
    const float* __restrict__ h_i_w, const float* __restrict__ h_i_b,
    const float* __restrict__ colsum,
    float* __restrict__ u_vec, float* __restrict__ i_vec)
{
    // arena: full B frag order [0, 65536). rev[4][50][68] (54.4KB) overlays it.
    __shared__ __align__(16) unsigned char arena[BFULL];
    __shared__ float lds_logit[NE][NR + 2];

    const int tid = threadIdx.x, wave = tid >> 6, lane = tid & 63;
    const int g = lane >> 4, c16 = lane & 15;

    const int E0 = blockIdx.x * NE;         // 4 consecutive elems, same branch
    const int branch = E0 >> 11;            // 0 = user, 1 = item

    const int*   ids     = branch ? item           : user;
    const float* r_topic = branch ? item_r_topic   : user_r_topic;
    const float* emb_w   = branch ? item_embed_w   : user_embed_w;
    const float* att_w   = branch ? item_att_w     : user_att_w;
    const unsigned short* fhi = branch ? fihi : fuhi;
    const float* fc_a_b  = branch ? fc_i_b         : fc_u_b;
    const float* fc_r_b  = branch ? fc_ri_b        : fc_ru_b;
    const float* h_w     = branch ? h_i_w          : h_u_w;
    const float* h_b     = branch ? h_i_b          : h_u_b;
    float*       out_vec = branch ? i_vec          : u_vec;

    const int rowg = wave * 16 + c16;
    const int rowc = rowg < NR ? rowg : NR - 1;

    int bidx[NE], idv[NE];
    const float* arowp[NE];
#pragma unroll
    for (int e = 0; e < NE; ++e) {
        bidx[e] = (E0 + e) & (NB - 1);
        idv[e]  = ids[bidx[e]];
        arowp[e] = r_topic + (size_t)bidx[e] * NR * NT;
    }

    f32x4 acc[NE][4];
#pragma unroll
    for (int e = 0; e < NE; ++e)
#pragma unroll
        for (int n = 0; n < 4; ++n) acc[e][n] = (f32x4){0.f, 0.f, 0.f, 0.f};

    // one kstep for one elem: kk = 0..15 global; f = A frag; e literal
    auto kstep = [&](int kk, bf16x8 f, int e) {
#pragma unroll
        for (int n = 0; n < 4; ++n) {
            bf16x8 bh = *reinterpret_cast<const bf16x8*>(
                arena + (size_t)((kk * 4 + n) * 64 + lane) * 16);
            acc[e][n] = __builtin_amdgcn_mfma_f32_16x16x32_bf16(f, bh, acc[e][n], 0, 0, 0);
        }
    };

    // ---- stage FULL B (64KB, once) + prologue A ----
    {
#pragma unroll
        for (int i = 0; i < 16; ++i) {
            size_t off = (size_t)(i * 256 + tid) * 16;
            gload16((const unsigned char*)bhi + off, arena + off);
        }
    }
    AISS16(A0, 0, 0)                        // out: 16B + 16 = 32
    AISS16(A1, 1, 0)                        // out: 48
    asm volatile("s_waitcnt vmcnt(32)" ::: "memory");   // B fully landed
    __builtin_amdgcn_sched_barrier(0);
    __builtin_amdgcn_s_barrier();           // B visible block-wide
    __builtin_amdgcn_sched_barrier(0);

    // ---- rolling pipeline: retire X | issue X+1 | compute X ----
    ARETH(A0) AISS16(A2, 2, 0) QCOMP8(A0, 0, 0)
    ARETH(A1) AISS16(A3, 3, 0) QCOMP8(A1, 1, 0)
    ARETH(A2) AISS16(B0, 0, 1) QCOMP8(A2, 2, 0)
    ARETH(A3) AISS16(B1, 1, 1) QCOMP8(A3, 3, 0)
    ARETH(B0) AISS16(B2, 2, 1) QCOMP8(B0, 0, 1)
    ARETH(B1) AISS16(B3, 3, 1) QCOMP8(B1, 1, 1)
    ARETH(B2)                  QCOMP8(B2, 2, 1)
    ARETL(B3)                  QCOMP8(B3, 3, 1)

    __syncthreads();                        // all B reads done -> overlay rev
    float (*rev)[NR][REVP] = reinterpret_cast<float(*)[NR][REVP]>(arena);
#pragma unroll
    for (int e = 0; e < NE; ++e)
#pragma unroll
        for (int n = 0; n < 4; ++n)
#pragma unroll
            for (int r4 = 0; r4 < 4; ++r4) {
                int r = wave * 16 + g * 4 + r4;
                if (r < NR) rev[e][r][n * 16 + c16] = acc[e][n][r4];
            }
    // no barrier: epilogue reads only this wave's own rows

    // ---- epilogue s-matmul: s[e][50x64] = review@fcR + att@fcA (K=128) ----
    f32x4 s4[NE][4];
#pragma unroll
    for (int e = 0; e < NE; ++e)
#pragma unroll
        for (int n = 0; n < 4; ++n) s4[e][n] = (f32x4){0.f, 0.f, 0.f, 0.f};

#pragma unroll
    for (int kk2 = 0; kk2 < 4; ++kk2) {
        bf16x8 bh[4];
#pragma unroll
        for (int n = 0; n < 4; ++n)
            bh[n] = *(reinterpret_cast<const bf16x8*>(fhi + (size_t)(kk2 * 4 + n) * 512) + lane);
#pragma unroll
        for (int e = 0; e < NE; ++e) {
            bf16x8 ah;
            if (kk2 < 2) {
                const float* rp = &rev[e][rowc][kk2 * 32 + g * 8];
                ah = cvt8_rne(*reinterpret_cast<const float4*>(rp),
                              *reinterpret_cast<const float4*>(rp + 4));
            } else {
                const float* ap = att_w + (size_t)idv[e] * ND + (kk2 - 2) * 32 + g * 8;
                ah = cvt8_rne(*reinterpret_cast<const float4*>(ap),
                              *reinterpret_cast<const float4*>(ap + 4));
            }
#pragma unroll
            for (int n = 0; n < 4; ++n)
                s4[e][n] = __builtin_amdgcn_mfma_f32_16x16x32_bf16(ah, bh[n], s4[e][n], 0, 0, 0);
        }
    }

    // bias + relu + dot with h_w, 16-lane reduce -> logits (per element)
    const float hb = h_b[0];
#pragma unroll
    for (int e = 0; e < NE; ++e) {
        float p0 = 0.f, p1 = 0.f, p2 = 0.f, p3 = 0.f;
#pragma unroll
        for (int n = 0; n < 4; ++n) {
            float hwn = h_w[n * 16 + c16];
            float bs = fc_r_b[n * 16 + c16] + fc_a_b[n * 16 + c16];
            p0 = fmaf(fmaxf(s4[e][n][0] + bs, 0.f), hwn, p0);
            p1 = fmaf(fmaxf(s4[e][n][1] + bs, 0.f), hwn, p1);
            p2 = fmaf(fmaxf(s4[e][n][2] + bs, 0.f), hwn, p2);
            p3 = fmaf(fmaxf(s4[e][n][3] + bs, 0.f), hwn, p3);
        }
#pragma unroll
        for (int off = 1; off < 16; off <<= 1) {
            p0 += __shfl_xor(p0, off);
            p1 += __shfl_xor(p1, off);
            p2 += __shfl_xor(p2, off);
            p3 += __shfl_xor(p3, off);
        }
        if (c16 == 0) {
            int rb = wave * 16 + g * 4;
            if (rb + 0 < NR) lds_logit[e][rb + 0] = p0 + hb;
            if (rb + 1 < NR) lds_logit[e][rb + 1] = p1 + hb;
            if (rb + 2 < NR) lds_logit[e][rb + 2] = p2 + hb;
            if (rb + 3 < NR) lds_logit[e][rb + 3] = p3 + hb;
        }
    }
    __syncthreads();   // publish rev rows + logits

    // softmax + pooling + colsum scale + emb add (wave e -> elem e)
    {
        const int e = wave;
        const int b = bidx[e];
        const int id = idv[e];
        float m = -1e30f;
        for (int r = 0; r < NR; ++r) m = fmaxf(m, lds_logit[e][r]);
        float sum = 0.f;
        for (int r = 0; r < NR; ++r) sum += __expf(lds_logit[e][r] - m);
        float inv = 1.f / sum;
        float feat = 0.f;
        for (int r = 0; r < NR; ++r)
            feat = fmaf(__expf(lds_logit[e][r] - m), rev[e][r][lane], feat);
        feat *= inv;
        out_vec[(size_t)b * ND + lane] = feat * colsum[lane] + emb_w[(size_t)id * ND + lane];
    }
}

// ---------------------------------------------------------------------------
__global__ __launch_bounds__(64) void final_kernel(
    const float* __restrict__ u_vec, const float* __restrict__ i_vec,
    const float* __restrict__ fc_pre_w, const float* __restrict__ fc_pre_b,
    float* __restrict__ out)
{
    int b = blockIdx.x, lane = threadIdx.x;
    float v = u_vec[(size_t)b * ND + lane] * fc_pre_w[lane]
            + i_vec[(size_t)b * ND + lane] * fc_pre_w[ND + lane];
#pragma unroll
    for (int off = 32; off; off >>= 1) v += __shfl_xor(v, off);
    if (lane == 0) out[b] = fmaxf(v + fc_pre_b[0], 0.f);
}

// ---------------------------------------------------------------------------
extern "C" void kernel_launch(void* const* d_in, const int* in_sizes, int n_in,
                              void* d_out, int out_size, void* d_ws, size_t ws_size,
                              hipStream_t stream) {
    (void)in_sizes; (void)n_in; (void)out_size; (void)ws_size;

    const int*   user         = (const int*)d_in[0];
    const int*   item         = (const int*)d_in[1];
    const float* user_r_topic = (const float*)d_in[2];
    const float* item_r_topic = (const float*)d_in[3];
    const float* user_embed_w = (const float*)d_in[4];
    const float* item_embed_w = (const float*)d_in[5];
    const float* user_att_w   = (const float*)d_in[6];
    const float* item_att_w   = (const float*)d_in[7];
    const float* topic_w      = (const float*)d_in[8];
    const float* fc_u_w       = (const float*)d_in[9];
    const float* fc_u_b       = (const float*)d_in[10];
    const float* fc_ru_w      = (const float*)d_in[11];
    const float* fc_ru_b      = (const float*)d_in[12];
    const float* fc_i_w       = (const float*)d_in[13];
    const float* fc_i_b       = (const float*)d_in[14];
    const float* fc_ri_w      = (const float*)d_in[15];
    const float* fc_ri_b      = (const float*)d_in[16];
    const float* h_u_w        = (const float*)d_in[17];
    const float* h_u_b        = (const float*)d_in[18];
    const float* h_i_w        = (const float*)d_in[19];
    const float* h_i_b        = (const float*)d_in[20];
    const float* fc_pre_w     = (const float*)d_in[21];
    const float* fc_pre_b     = (const float*)d_in[22];

    // workspace layout
    unsigned short* bhi  = (unsigned short*)d_ws;      // 32768
    unsigned short* fuhi = bhi + 32768;                // 8192
    unsigned short* fihi = fuhi + 8192;                // 8192
    float* colsum = (float*)(fihi + 8192);             // 64
    float* u_vec  = colsum + 64;                       // NB*ND
    float* i_vec  = u_vec + NB * ND;                   // NB*ND

    prep_kernel<<<192, 256, 0, stream>>>(topic_w, fc_u_w, fc_ru_w, fc_i_w, fc_ri_w,
                                         bhi, fuhi, fihi);
    colsum_kernel<<<1, 256, 0, stream>>>(topic_w, colsum);

    branch_kernel<<<(2 * NB) / NE, 256, 0, stream>>>(
        user, item, user_r_topic, item_r_topic,
        user_embed_w, item_embed_w, user_att_w, item_att_w,
        bhi, fuhi, fihi,
        fc_u_b, fc_ru_b, fc_i_b, fc_ri_b,
        h_u_w, h_u_b, h_i_w, h_i_b,
        colsum, u_vec, i_vec);

    final_kernel<<<NB, 64, 0, stream>>>(u_vec, i_vec, fc_pre_w, fc_pre_b,
                                        (float*)d_out);
}

// Round 21
// 124.980 us; speedup vs baseline: 1.0227x; 1.0227x over previous
//
#include <hip/hip_runtime.h>
#include <cstdint>
#include <cstddef>

#define NB 2048
#define NT 512
#define ND 64
#define NR 50
#define NE 2             // batch elements per block
#define REVP 68          // review row stride (floats)
#define BH 32768         // B-half LDS bytes

typedef __attribute__((ext_vector_type(8))) short bf16x8;
typedef __attribute__((ext_vector_type(4))) float f32x4;

__device__ inline unsigned short f2bf_rne(float x) {
    unsigned int u = __float_as_uint(x);
    u += 0x7fffu + ((u >> 16) & 1u);
    return (unsigned short)(u >> 16);
}

__device__ inline bf16x8 cvt8_rne(float4 v0, float4 v1) {
    union { unsigned int u[4]; bf16x8 v; } P;
    asm("v_cvt_pk_bf16_f32 %0, %1, %2" : "=v"(P.u[0]) : "v"(v0.x), "v"(v0.y));
    asm("v_cvt_pk_bf16_f32 %0, %1, %2" : "=v"(P.u[1]) : "v"(v0.z), "v"(v0.w));
    asm("v_cvt_pk_bf16_f32 %0, %1, %2" : "=v"(P.u[2]) : "v"(v1.x), "v"(v1.y));
    asm("v_cvt_pk_bf16_f32 %0, %1, %2" : "=v"(P.u[3]) : "v"(v1.z), "v"(v1.w));
    return P.v;
}

__device__ inline void gload16(const void* gsrc, void* ldst) {
    __builtin_amdgcn_global_load_lds(
        (const __attribute__((address_space(1))) unsigned int*)gsrc,
        (__attribute__((address_space(3))) unsigned int*)ldst, 16, 0, 0);
}

// ---------------------------------------------------------------------------
__global__ __launch_bounds__(256) void prep_kernel(
    const float* __restrict__ tw,
    const float* __restrict__ fc_u_w, const float* __restrict__ fc_ru_w,
    const float* __restrict__ fc_i_w, const float* __restrict__ fc_ri_w,
    unsigned short* __restrict__ bhi,
    unsigned short* __restrict__ fuhi, unsigned short* __restrict__ fihi)
{
    int i = blockIdx.x * 256 + threadIdx.x;          // 192*256 = 49152
    if (i < 32768) {
        int j  = i & 7;
        int l  = (i >> 3) & 63;
        int n  = (i >> 9) & 3;
        int kk = i >> 11;                            // 0..15
        int t = kk * 32 + ((l >> 4) << 3) + j;
        int d = n * 16 + (l & 15);
        bhi[i] = f2bf_rne(tw[t * ND + d]);
    } else {
        int q = i - 32768;                           // 0..16383
        int br = q >> 13;                            // 0 user, 1 item
        int e = q & 8191;
        int j  = e & 7;
        int l  = (e >> 3) & 63;
        int n  = (e >> 9) & 3;
        int kk = e >> 11;                            // 0..3
        int k = kk * 32 + ((l >> 4) << 3) + j;       // 0..127
        int col = n * 16 + (l & 15);
        const float* W = (k < 64) ? (br ? fc_ri_w : fc_ru_w)
                                  : (br ? fc_i_w  : fc_u_w);
        unsigned short hi = f2bf_rne(W[(k & 63) * ND + col]);
        if (br) fihi[e] = hi; else fuhi[e] = hi;
    }
}

// ---------------------------------------------------------------------------
__global__ __launch_bounds__(256) void colsum_kernel(const float* __restrict__ tw,
                                                     float* __restrict__ colsum) {
    __shared__ float part[4][ND];
    int d = threadIdx.x & 63, p = threadIdx.x >> 6;
    float s = 0.f;
    for (int t = p; t < NT; t += 4) s += tw[t * ND + d];
    part[p][d] = s;
    __syncthreads();
    if (threadIdx.x < ND)
        colsum[d] = part[0][d] + part[1][d] + part[2][d] + part[3][d];
}

// pinned issue of ONE kstep's A fragment (8 floats of this lane's own row)
#define AISS2(T, e, COL)                                                       \
    float4 aA_##T##_0, aA_##T##_1;                                             \
    {                                                                          \
        const float* _p = arowp[e] + (size_t)rowc * NT + (COL);                \
        asm volatile("global_load_dwordx4 %0, %1, off"                         \
                     : "=v"(aA_##T##_0) : "v"(_p) : "memory");                 \
        asm volatile("global_load_dwordx4 %0, %1, off"                         \
                     : "=v"(aA_##T##_1) : "v"(_p + 4) : "memory");             \
    }
// 8 loads = one elem's quarter (4 ksteps)
#define AISS8(T, e, h, qh)                                                     \
    AISS2(T##_0, e, (h) * 256 + ((qh) * 4 + 0) * 32 + g * 8)                   \
    AISS2(T##_1, e, (h) * 256 + ((qh) * 4 + 1) * 32 + g * 8)                   \
    AISS2(T##_2, e, (h) * 256 + ((qh) * 4 + 2) * 32 + g * 8)                   \
    AISS2(T##_3, e, (h) * 256 + ((qh) * 4 + 3) * 32 + g * 8)

// interlocked retire+convert -> bf16x8 fragment fr_<T>.v (retires 2 loads)
#define FRAG(T, N)                                                             \
    union { unsigned int u[4]; bf16x8 v; } fr_##T;                             \
    asm volatile("s_waitcnt vmcnt(" #N ")\n\t"                                 \
                 "v_cvt_pk_bf16_f32 %0, %4, %5\n\t"                            \
                 "v_cvt_pk_bf16_f32 %1, %6, %7\n\t"                            \
                 "v_cvt_pk_bf16_f32 %2, %8, %9\n\t"                            \
                 "v_cvt_pk_bf16_f32 %3, %10, %11"                              \
                 : "=&v"(fr_##T.u[0]), "=&v"(fr_##T.u[1]),                     \
                   "=&v"(fr_##T.u[2]), "=&v"(fr_##T.u[3])                      \
                 : "v"(aA_##T##_0.x), "v"(aA_##T##_0.y),                       \
                   "v"(aA_##T##_0.z), "v"(aA_##T##_0.w),                       \
                   "v"(aA_##T##_1.x), "v"(aA_##T##_1.y),                       \
                   "v"(aA_##T##_1.z), "v"(aA_##T##_1.w)                        \
                 : "memory");
// retire one 8-load chunk with K loads still behind it (ladders)
#define RETQ22(T) FRAG(T##_0, 22) FRAG(T##_1, 20) FRAG(T##_2, 18) FRAG(T##_3, 16)
#define RETQ30(T) FRAG(T##_0, 30) FRAG(T##_1, 28) FRAG(T##_2, 26) FRAG(T##_3, 24)
#define RETQ14(T) FRAG(T##_0, 14) FRAG(T##_1, 12) FRAG(T##_2, 10) FRAG(T##_3, 8)
#define RETQ6(T)  FRAG(T##_0, 6)  FRAG(T##_1, 4)  FRAG(T##_2, 2)  FRAG(T##_3, 0)
// compute one chunk (4 ksteps of elem e in B-half slot qh)
#define QCOMP4(T, e, qh)                                                       \
    kstep((qh) * 4 + 0, fr_##T##_0.v, e); kstep((qh) * 4 + 1, fr_##T##_1.v, e);\
    kstep((qh) * 4 + 2, fr_##T##_2.v, e); kstep((qh) * 4 + 3, fr_##T##_3.v, e);

// ---------------------------------------------------------------------------
// Block = 4 waves x 2 batch elements (grid 2048), 3 blocks/CU (12 waves).
// r19 base + ROLLING 24-load pinned window: retire chunk X || issue X+3 ||
// compute X. No fully-exposed load latency except the prologue.
__global__ __launch_bounds__(256, 3) void branch_kernel(
    const int* __restrict__ user, const int* __restrict__ item,
    const float* __restrict__ user_r_topic, const float* __restrict__ item_r_topic,
    const float* __restrict__ user_embed_w, const float* __restrict__ item_embed_w,
    const float* __restrict__ user_att_w, const float* __restrict__ item_att_w,
    const unsigned short* __restrict__ bhi,
    const unsigned short* __restrict__ fuhi, const unsigned short* __restrict__ fihi,
    const float* __restrict__ fc_u_b, const float* __restrict__ fc_ru_b,
    const float* __restrict__ fc_i_b, const float* __restrict__ fc_ri_b,
    const float* __restrict__ h_u_w, const float* __restrict__ h_u_b,
    const float* __restrict__ h_i_w, const float* __restrict__ h_i_b,
    const float* __restrict__ colsum,
    float* __restrict__ u_vec, float* __restrict__ i_vec)
{
    // arena: B-half frag order [0, 32768). rev[2][50][68] (27.2KB) overlays it.
    __shared__ __align__(16) unsigned char arena[BH];
    __shared__ float lds_logit[NE][NR + 2];

    const int tid = threadIdx.x, wave = tid >> 6, lane = tid & 63;
    const int g = lane >> 4, c16 = lane & 15;

    const int E0 = blockIdx.x * NE;         // 2 consecutive elems, same branch
    const int branch = E0 >> 11;            // 0 = user, 1 = item

    const int*   ids     = branch ? item           : user;
    const float* r_topic = branch ? item_r_topic   : user_r_topic;
    const float* emb_w   = branch ? item_embed_w   : user_embed_w;
    const float* att_w   = branch ? item_att_w     : user_att_w;
    const unsigned short* fhi = branch ? fihi : fuhi;
    const float* fc_a_b  = branch ? fc_i_b         : fc_u_b;
    const float* fc_r_b  = branch ? fc_ri_b        : fc_ru_b;
    const float* h_w     = branch ? h_i_w          : h_u_w;
    const float* h_b     = branch ? h_i_b          : h_u_b;
    float*       out_vec = branch ? i_vec          : u_vec;

    const int rowg = wave * 16 + c16;
    const int rowc = rowg < NR ? rowg : NR - 1;

    int bidx[NE], idv[NE];
    const float* arowp[NE];
#pragma unroll
    for (int e = 0; e < NE; ++e) {
        bidx[e] = (E0 + e) & (NB - 1);
        idv[e]  = ids[bidx[e]];
        arowp[e] = r_topic + (size_t)bidx[e] * NR * NT;
    }

    // stage one 32KB B-half (8 x 16B per thread, coalesced)
    auto stageB = [&](int h) {
        const unsigned char* src = (const unsigned char*)bhi + (size_t)h * BH;
#pragma unroll
        for (int i = 0; i < 8; ++i) {
            size_t off = (size_t)(i * 256 + tid) * 16;
            gload16(src + off, arena + off);
        }
    };

    f32x4 acc[NE][4];
#pragma unroll
    for (int e = 0; e < NE; ++e)
#pragma unroll
        for (int n = 0; n < 4; ++n) acc[e][n] = (f32x4){0.f, 0.f, 0.f, 0.f};

    // one kstep: klq = kstep index within half (0..7); f = A frag; e literal
    auto kstep = [&](int klq, bf16x8 f, int e) {
#pragma unroll
        for (int n = 0; n < 4; ++n) {
            bf16x8 bh = *reinterpret_cast<const bf16x8*>(
                arena + (size_t)((klq * 4 + n) * 64 + lane) * 16);
            acc[e][n] = __builtin_amdgcn_mfma_f32_16x16x32_bf16(f, bh, acc[e][n], 0, 0, 0);
        }
    };

    // chunks: c0=(e0,h0,q0) c1=(e1,h0,q0) c2=(e0,h0,q1) c3=(e1,h0,q1)
    //         c4=(e0,h1,q0) c5=(e1,h1,q0) c6=(e0,h1,q1) c7=(e1,h1,q1)
    // ---- prologue ----
    stageB(0);                               // out: B 8
    AISS8(c0, 0, 0, 0) AISS8(c1, 1, 0, 0)    // out: 24
    asm volatile("s_waitcnt vmcnt(16)" ::: "memory");   // B half0 landed
    __builtin_amdgcn_sched_barrier(0);
    __builtin_amdgcn_s_barrier();            // B half0 visible
    __builtin_amdgcn_sched_barrier(0);

    // ---- half0: rolling window ----
    AISS8(c2, 0, 0, 1)                       // c0,c1,c2 = 24
    RETQ22(c0) QCOMP4(c0, 0, 0)
    AISS8(c3, 1, 0, 1)                       // c1,c2,c3 = 24
    RETQ22(c1) QCOMP4(c1, 1, 0)
    AISS8(c4, 0, 1, 0)                       // c2,c3,c4 = 24
    RETQ22(c2) QCOMP4(c2, 0, 1)
    AISS8(c5, 1, 1, 0)                       // c3,c4,c5 = 24
    RETQ22(c3) QCOMP4(c3, 1, 1)
    __builtin_amdgcn_sched_barrier(0);
    __builtin_amdgcn_s_barrier();            // all waves done reading B half0
    __builtin_amdgcn_sched_barrier(0);

    // ---- half transition ----
    stageB(1);                               // out: c4(8), c5(8), B(8) = 24
    AISS8(c6, 0, 1, 1)                       // out: 32
    RETQ30(c4)                               // c4 retired (<=24 left)
    RETQ22(c5)                               // c5 retired (<=16: B + c6)
    asm volatile("s_waitcnt vmcnt(8)" ::: "memory");    // B half1 landed
    __builtin_amdgcn_sched_barrier(0);
    __builtin_amdgcn_s_barrier();            // B half1 visible
    __builtin_amdgcn_sched_barrier(0);

    // ---- half1 ----
    QCOMP4(c4, 0, 0)
    AISS8(c7, 1, 1, 1)                       // c6,c7 = 16
    QCOMP4(c5, 1, 0)
    RETQ14(c6) QCOMP4(c6, 0, 1)
    RETQ6(c7)  QCOMP4(c7, 1, 1)

    __syncthreads();                         // all B reads done -> overlay rev
    float (*rev)[NR][REVP] = reinterpret_cast<float(*)[NR][REVP]>(arena);
#pragma unroll
    for (int e = 0; e < NE; ++e)
#pragma unroll
        for (int n = 0; n < 4; ++n)
#pragma unroll
            for (int r4 = 0; r4 < 4; ++r4) {
                int r = wave * 16 + g * 4 + r4;
                if (r < NR) rev[e][r][n * 16 + c16] = acc[e][n][r4];
            }
    // no barrier: epilogue reads only this wave's own rows

    // ---- epilogue s-matmul: s[e][50x64] = review@fcR + att@fcA (K=128) ----
    f32x4 s4[NE][4];
#pragma unroll
    for (int e = 0; e < NE; ++e)
#pragma unroll
        for (int n = 0; n < 4; ++n) s4[e][n] = (f32x4){0.f, 0.f, 0.f, 0.f};

#pragma unroll
    for (int kk2 = 0; kk2 < 4; ++kk2) {
        bf16x8 bh[4];
#pragma unroll
        for (int n = 0; n < 4; ++n)
            bh[n] = *(reinterpret_cast<const bf16x8*>(fhi + (size_t)(kk2 * 4 + n) * 512) + lane);
#pragma unroll
        for (int e = 0; e < NE; ++e) {
            bf16x8 ah;
            if (kk2 < 2) {
                const float* rp = &rev[e][rowc][kk2 * 32 + g * 8];
                ah = cvt8_rne(*reinterpret_cast<const float4*>(rp),
                              *reinterpret_cast<const float4*>(rp + 4));
            } else {
                const float* ap = att_w + (size_t)idv[e] * ND + (kk2 - 2) * 32 + g * 8;
                ah = cvt8_rne(*reinterpret_cast<const float4*>(ap),
                              *reinterpret_cast<const float4*>(ap + 4));
            }
#pragma unroll
            for (int n = 0; n < 4; ++n)
                s4[e][n] = __builtin_amdgcn_mfma_f32_16x16x32_bf16(ah, bh[n], s4[e][n], 0, 0, 0);
        }
    }

    // bias + relu + dot with h_w, 16-lane reduce -> logits (per element)
    const float hb = h_b[0];
#pragma unroll
    for (int e = 0; e < NE; ++e) {
        float p0 = 0.f, p1 = 0.f, p2 = 0.f, p3 = 0.f;
#pragma unroll
        for (int n = 0; n < 4; ++n) {
            float hwn = h_w[n * 16 + c16];
            float bs = fc_r_b[n * 16 + c16] + fc_a_b[n * 16 + c16];
            p0 = fmaf(fmaxf(s4[e][n][0] + bs, 0.f), hwn, p0);
            p1 = fmaf(fmaxf(s4[e][n][1] + bs, 0.f), hwn, p1);
            p2 = fmaf(fmaxf(s4[e][n][2] + bs, 0.f), hwn, p2);
            p3 = fmaf(fmaxf(s4[e][n][3] + bs, 0.f), hwn, p3);
        }
#pragma unroll
        for (int off = 1; off < 16; off <<= 1) {
            p0 += __shfl_xor(p0, off);
            p1 += __shfl_xor(p1, off);
            p2 += __shfl_xor(p2, off);
            p3 += __shfl_xor(p3, off);
        }
        if (c16 == 0) {
            int rb = wave * 16 + g * 4;
            if (rb + 0 < NR) lds_logit[e][rb + 0] = p0 + hb;
            if (rb + 1 < NR) lds_logit[e][rb + 1] = p1 + hb;
            if (rb + 2 < NR) lds_logit[e][rb + 2] = p2 + hb;
            if (rb + 3 < NR) lds_logit[e][rb + 3] = p3 + hb;
        }
    }
    __syncthreads();   // publish rev rows + logits

    // softmax + pooling + colsum scale + emb add (wave e -> elem e)
    if (wave < NE) {
        const int e = wave;
        const int b = bidx[e];
        const int id = idv[e];
        float m = -1e30f;
        for (int r = 0; r < NR; ++r) m = fmaxf(m, lds_logit[e][r]);
        float sum = 0.f;
        for (int r = 0; r < NR; ++r) sum += __expf(lds_logit[e][r] - m);
        float inv = 1.f / sum;
        float feat = 0.f;
        for (int r = 0; r < NR; ++r)
            feat = fmaf(__expf(lds_logit[e][r] - m), rev[e][r][lane], feat);
        feat *= inv;
        out_vec[(size_t)b * ND + lane] = feat * colsum[lane] + emb_w[(size_t)id * ND + lane];
    }
}

// ---------------------------------------------------------------------------
__global__ __launch_bounds__(64) void final_kernel(
    const float* __restrict__ u_vec, const float* __restrict__ i_vec,
    const float* __restrict__ fc_pre_w, const float* __restrict__ fc_pre_b,
    float* __restrict__ out)
{
    int b = blockIdx.x, lane = threadIdx.x;
    float v = u_vec[(size_t)b * ND + lane] * fc_pre_w[lane]
            + i_vec[(size_t)b * ND + lane] * fc_pre_w[ND + lane];
#pragma unroll
    for (int off = 32; off; off >>= 1) v += __shfl_xor(v, off);
    if (lane == 0) out[b] = fmaxf(v + fc_pre_b[0], 0.f);
}

// ---------------------------------------------------------------------------
extern "C" void kernel_launch(void* const* d_in, const int* in_sizes, int n_in,
                              void* d_out, int out_size, void* d_ws, size_t ws_size,
                              hipStream_t stream) {
    (void)in_sizes; (void)n_in; (void)out_size; (void)ws_size;

    const int*   user         = (const int*)d_in[0];
    const int*   item         = (const int*)d_in[1];
    const float* user_r_topic = (const float*)d_in[2];
    const float* item_r_topic = (const float*)d_in[3];
    const float* user_embed_w = (const float*)d_in[4];
    const float* item_embed_w = (const float*)d_in[5];
    const float* user_att_w   = (const float*)d_in[6];
    const float* item_att_w   = (const float*)d_in[7];
    const float* topic_w      = (const float*)d_in[8];
    const float* fc_u_w       = (const float*)d_in[9];
    const float* fc_u_b       = (const float*)d_in[10];
    const float* fc_ru_w      = (const float*)d_in[11];
    const float* fc_ru_b      = (const float*)d_in[12];
    const float* fc_i_w       = (const float*)d_in[13];
    const float* fc_i_b       = (const float*)d_in[14];
    const float* fc_ri_w      = (const float*)d_in[15];
    const float* fc_ri_b      = (const float*)d_in[16];
    const float* h_u_w        = (const float*)d_in[17];
    const float* h_u_b        = (const float*)d_in[18];
    const float* h_i_w        = (const float*)d_in[19];
    const float* h_i_b        = (const float*)d_in[20];
    const float* fc_pre_w     = (const float*)d_in[21];
    const float* fc_pre_b     = (const float*)d_in[22];

    // workspace layout
    unsigned short* bhi  = (unsigned short*)d_ws;      // 32768
    unsigned short* fuhi = bhi + 32768;                // 8192
    unsigned short* fihi = fuhi + 8192;                // 8192
    float* colsum = (float*)(fihi + 8192);             // 64
    float* u_vec  = colsum + 64;                       // NB*ND
    float* i_vec  = u_vec + NB * ND;                   // NB*ND

    prep_kernel<<<192, 256, 0, stream>>>(topic_w, fc_u_w, fc_ru_w, fc_i_w, fc_ri_w,
                                         bhi, fuhi, fihi);
    colsum_kernel<<<1, 256, 0, stream>>>(topic_w, colsum);

    branch_kernel<<<(2 * NB) / NE, 256, 0, stream>>>(
        user, item, user_r_topic, item_r_topic,
        user_embed_w, item_embed_w, user_att_w, item_att_w,
        bhi, fuhi, fihi,
        fc_u_b, fc_ru_b, fc_i_b, fc_ri_b,
        h_u_w, h_u_b, h_i_w, h_i_b,
        colsum, u_vec, i_vec);

    final_kernel<<<NB, 64, 0, stream>>>(u_vec, i_vec, fc_pre_w, fc_pre_b,
                                        (float*)d_out);
}